// Round 3
// baseline (3592.837 us; speedup 1.0000x reference)
//
#include <hip/hip_runtime.h>
#include <cmath>

#define FILT 11

struct GW { float w[FILT]; };

// ---- order-preserving float<->uint encode for atomic min/max ----
__device__ __forceinline__ unsigned enc_f(float f) {
    unsigned u = __float_as_uint(f);
    return (u & 0x80000000u) ? ~u : (u | 0x80000000u);
}
__device__ __forceinline__ float dec_f(unsigned u) {
    return (u & 0x80000000u) ? __uint_as_float(u & 0x7FFFFFFFu)
                             : __uint_as_float(~u);
}

__global__ void init_acc(unsigned* ws) {
    int t = threadIdx.x;
    if (t == 0) { ws[0] = 0u; ws[1] = 0xFFFFFFFFu; }
    for (int i = 2 + t; i < 512; i += blockDim.x) ws[i] = 0u;  // float 0.0
}

__global__ void minmax_kernel(const float4* __restrict__ t, long n4, unsigned* mm) {
    unsigned mx = 0u, mn = 0xFFFFFFFFu;
    long stride = (long)gridDim.x * blockDim.x;
    for (long i = (long)blockIdx.x * blockDim.x + threadIdx.x; i < n4; i += stride) {
        float4 v = t[i];
        unsigned a = enc_f(v.x), b = enc_f(v.y), c = enc_f(v.z), d = enc_f(v.w);
        mx = max(mx, max(max(a, b), max(c, d)));
        mn = min(mn, min(min(a, b), min(c, d)));
    }
    for (int off = 32; off; off >>= 1) {
        mx = max(mx, (unsigned)__shfl_down((int)mx, off));
        mn = min(mn, (unsigned)__shfl_down((int)mn, off));
    }
    __shared__ unsigned smx[4], smn[4];
    int wid = threadIdx.x >> 6, lane = threadIdx.x & 63;
    if (lane == 0) { smx[wid] = mx; smn[wid] = mn; }
    __syncthreads();
    if (threadIdx.x == 0) {
        for (int i = 1; i < 4; i++) { mx = max(mx, smx[i]); mn = min(mn, smn[i]); }
        atomicMax(&mm[0], mx);
        atomicMin(&mm[1], mn);
    }
}

// Row-streaming fused SSIM + pool. One wave owns a 64-out-col strip x row band.
// No __syncthreads anywhere (waves are fully independent).
__global__ __launch_bounds__(256) void ssim_stream(
    const float* __restrict__ x, const float* __restrict__ y,
    int H, int W, int NC, int nstrips, int nb, int B,
    const unsigned* __restrict__ mm,
    float* __restrict__ cs_sum, float* __restrict__ ssim_sum, GW gw,
    float* __restrict__ poolx, float* __restrict__ pooly, int do_pool)
{
    __shared__ float2 ring[4][2][80];

    const int wv = threadIdx.x >> 6;
    const int lane = threadIdx.x & 63;
    const int wid = blockIdx.x * 4 + wv;
    const int total = NC * nstrips * nb;
    if (wid >= total) return;

    const int band = wid % nb;
    const int t1 = wid / nb;
    const int strip = t1 % nstrips;
    const int img = t1 / nstrips;
    const int n = img / 3;

    const int Ho = H - (FILT - 1);
    const int Wo = W - (FILT - 1);
    const int out_lo = band * B;
    const int out_hi = min(out_lo + B, Ho);
    if (out_lo >= Ho) return;
    const int a = out_lo, b = out_hi + (FILT - 1);  // input rows [a, b)

    const int base = strip * 64;
    const float* xp = x + (size_t)img * H * W;
    const float* yp = y + (size_t)img * H * W;
    const int c0 = min(base + lane, W - 1);
    const int c1 = min(base + 64 + lane, W - 1);
    const bool colv = (base + lane) < Wo;

    const float mv = dec_f(mm[0]) - dec_f(mm[1]);
    const float c1c = (0.01f * mv) * (0.01f * mv);
    const float c2c = (0.03f * mv) * (0.03f * mv);

    const int Wp = W >> 1;
    const size_t pbase = (size_t)img * (H >> 1) * Wp;

    float acc[FILT][5];
#pragma unroll
    for (int s = 0; s < FILT; s++)
#pragma unroll
        for (int q = 0; q < 5; q++) acc[s][q] = 0.f;

    float lcs = 0.f, lss = 0.f;

    for (int r0 = a; r0 < b; r0 += FILT) {
#pragma unroll
        for (int p = 0; p < FILT; p++) {
            const int r = r0 + p;
            if (r >= b) break;
            const int cur = r & 1;

            // ---- stage row r (x,y interleaved) into per-wave LDS ring ----
            const float* xr = xp + (size_t)r * W;
            const float* yr = yp + (size_t)r * W;
            float2 v0;
            v0.x = xr[c0]; v0.y = yr[c0];
            ring[wv][cur][lane] = v0;
            if (lane < 10) {
                float2 v1;
                v1.x = xr[c1]; v1.y = yr[c1];
                ring[wv][cur][64 + lane] = v1;
            }
            // cross-lane RAW within the wave: fence compiler + wait LDS
            __asm__ volatile("s_waitcnt lgkmcnt(0)" ::: "memory");

            // ---- horizontal 11-tap blur of x, y, x^2, y^2, xy ----
            float h0 = 0.f, h1 = 0.f, h2 = 0.f, h3 = 0.f, h4 = 0.f;
#pragma unroll
            for (int k = 0; k < FILT; k++) {
                float2 v = ring[wv][cur][lane + k];
                float w = gw.w[k];
                h0 += w * v.x;
                h1 += w * v.y;
                h2 += w * (v.x * v.x);
                h3 += w * (v.y * v.y);
                h4 += w * (v.x * v.y);
            }

            // ---- vertical ring accumulation (all indices static) ----
#pragma unroll
            for (int k = 0; k < FILT; k++) {
                const int s = (p - k + FILT) % FILT;
                float w = gw.w[k];
                acc[s][0] += w * h0;
                acc[s][1] += w * h1;
                acc[s][2] += w * h2;
                acc[s][3] += w * h3;
                acc[s][4] += w * h4;
            }

            // ---- emit completed output row ro = r-10 (slot e) ----
            const int e = (p + 1) % FILT;
            if (r >= a + (FILT - 1)) {
                if (colv) {
                    float m1 = acc[e][0], m2 = acc[e][1];
                    float mu11 = m1 * m1, mu22 = m2 * m2, mu12 = m1 * m2;
                    float s1 = acc[e][2] - mu11;
                    float s2 = acc[e][3] - mu22;
                    float s12 = acc[e][4] - mu12;
                    float cs = __fdividef(2.f * s12 + c2c, s1 + s2 + c2c);
                    float ss = __fdividef(2.f * mu12 + c1c, mu11 + mu22 + c1c) * cs;
                    lcs += cs;
                    lss += ss;
                }
            }
            acc[e][0] = acc[e][1] = acc[e][2] = acc[e][3] = acc[e][4] = 0.f;

            // ---- fused 2x2 avg pool on raw rows (r-1, r) ----
            if (do_pool && (r & 1) && r > a && lane < 32) {
                const int pc = (base >> 1) + lane;
                if (pc < Wp) {
                    float2 q00 = ring[wv][cur ^ 1][2 * lane];
                    float2 q01 = ring[wv][cur ^ 1][2 * lane + 1];
                    float2 q10 = ring[wv][cur][2 * lane];
                    float2 q11 = ring[wv][cur][2 * lane + 1];
                    size_t o = pbase + (size_t)(r >> 1) * Wp + pc;
                    poolx[o] = 0.25f * (q00.x + q01.x + q10.x + q11.x);
                    pooly[o] = 0.25f * (q00.y + q01.y + q10.y + q11.y);
                }
            }
        }
    }

    // ---- per-wave reduction + atomic ----
    for (int off = 32; off; off >>= 1) {
        lcs += __shfl_down(lcs, off);
        lss += __shfl_down(lss, off);
    }
    if (lane == 0) {
        atomicAdd(&cs_sum[n], lcs);
        atomicAdd(&ssim_sum[n], lss);
    }
}

__global__ void final_kernel(const float* __restrict__ cs_sum,
                             const float* __restrict__ ssim_sum,
                             float* __restrict__ out)
{
    const float cnt[5] = {3.f * 502 * 502, 3.f * 246 * 246, 3.f * 118 * 118,
                          3.f * 54 * 54, 3.f * 22 * 22};
    const float wts[5] = {0.0448f, 0.2856f, 0.3001f, 0.2363f, 0.1333f};
    int n = threadIdx.x;
    float ms = 0.f;
    if (n < 32) {
        float ssim = ssim_sum[4 * 32 + n] / cnt[4];
        float t = powf(ssim, wts[4]);
        ms = 1.f;
        for (int l = 0; l < 4; l++) {
            float cs = cs_sum[l * 32 + n] / cnt[l];
            ms *= powf(cs, wts[l]) * t;  // faithful: ssim^w4 inside the product
        }
    }
    for (int off = 32; off; off >>= 1) ms += __shfl_down(ms, off);
    if (threadIdx.x == 0) out[0] = ms / 32.f;
}

extern "C" void kernel_launch(void* const* d_in, const int* in_sizes, int n_in,
                              void* d_out, int out_size, void* d_ws, size_t ws_size,
                              hipStream_t stream) {
    const float* x0 = (const float*)d_in[0];
    const float* y0 = (const float*)d_in[1];
    float* out = (float*)d_out;
    float* ws = (float*)d_ws;
    unsigned* mm = (unsigned*)d_ws;
    float* cs_sum = ws + 2;
    float* ssim_sum = ws + 2 + 5 * 32;

    const int N = 32, C = 3, NC = N * C;
    const int Hs[5] = {512, 256, 128, 64, 32};

    // pyramid buffers in ws (floats), after 512-float accumulator area
    float* wp = ws + 512;
    float* pxw[5] = {nullptr, nullptr, nullptr, nullptr, nullptr};
    float* pyw[5] = {nullptr, nullptr, nullptr, nullptr, nullptr};
    for (int l = 1; l < 5; l++) {
        size_t sz = (size_t)NC * Hs[l] * Hs[l];
        pxw[l] = wp; wp += sz;
        pyw[l] = wp; wp += sz;
    }
    const float* px[5] = {x0, pxw[1], pxw[2], pxw[3], pxw[4]};
    const float* py[5] = {y0, pyw[1], pyw[2], pyw[3], pyw[4]};

    // gaussian weights (softmax of -c^2/(2*sigma^2))
    GW gw;
    {
        double tmp[FILT], s = 0.0;
        for (int k = 0; k < FILT; k++) {
            double c = (double)k - (FILT - 1) / 2.0;
            tmp[k] = exp(-c * c / (2.0 * 1.5 * 1.5));
            s += tmp[k];
        }
        for (int k = 0; k < FILT; k++) gw.w[k] = (float)(tmp[k] / s);
    }

    init_acc<<<1, 256, 0, stream>>>(mm);
    long n4 = (long)NC * 512 * 512 / 4;
    minmax_kernel<<<1024, 256, 0, stream>>>((const float4*)y0, n4, mm);

    for (int l = 0; l < 5; l++) {
        int H = Hs[l];
        int Ho = H - (FILT - 1);
        int nstrips = (Ho + 63) / 64;
        int nb = (Ho + 63) / 64;
        int B = (Ho + nb - 1) / nb;
        int total_waves = NC * nstrips * nb;
        int grid = (total_waves + 3) / 4;
        int do_pool = (l < 4) ? 1 : 0;
        ssim_stream<<<grid, 256, 0, stream>>>(
            px[l], py[l], H, H, NC, nstrips, nb, B, mm,
            cs_sum + l * 32, ssim_sum + l * 32, gw,
            do_pool ? pxw[l + 1] : nullptr,
            do_pool ? pyw[l + 1] : nullptr, do_pool);
    }
    final_kernel<<<1, 64, 0, stream>>>(cs_sum, ssim_sum, out);
}

// Round 4
// 486.050 us; speedup vs baseline: 7.3919x; 7.3919x over previous
//
#include <hip/hip_runtime.h>
#include <cmath>

#define FILT 11

struct GW { float w[FILT]; };

// ---- order-preserving float<->uint encode for atomic min/max ----
__device__ __forceinline__ unsigned enc_f(float f) {
    unsigned u = __float_as_uint(f);
    return (u & 0x80000000u) ? ~u : (u | 0x80000000u);
}
__device__ __forceinline__ float dec_f(unsigned u) {
    return (u & 0x80000000u) ? __uint_as_float(u & 0x7FFFFFFFu)
                             : __uint_as_float(~u);
}

__global__ void init_acc(unsigned* ws) {
    int t = threadIdx.x;
    if (t == 0) { ws[0] = 0u; ws[1] = 0xFFFFFFFFu; }
    for (int i = 2 + t; i < 512; i += blockDim.x) ws[i] = 0u;  // float 0.0
}

__global__ void minmax_kernel(const float4* __restrict__ t, long n4, unsigned* mm) {
    unsigned mx = 0u, mn = 0xFFFFFFFFu;
    long stride = (long)gridDim.x * blockDim.x;
    for (long i = (long)blockIdx.x * blockDim.x + threadIdx.x; i < n4; i += stride) {
        float4 v = t[i];
        unsigned a = enc_f(v.x), b = enc_f(v.y), c = enc_f(v.z), d = enc_f(v.w);
        mx = max(mx, max(max(a, b), max(c, d)));
        mn = min(mn, min(min(a, b), min(c, d)));
    }
    for (int off = 32; off; off >>= 1) {
        mx = max(mx, (unsigned)__shfl_down((int)mx, off));
        mn = min(mn, (unsigned)__shfl_down((int)mn, off));
    }
    __shared__ unsigned smx[4], smn[4];
    int wid = threadIdx.x >> 6, lane = threadIdx.x & 63;
    if (lane == 0) { smx[wid] = mx; smn[wid] = mn; }
    __syncthreads();
    if (threadIdx.x == 0) {
        for (int i = 1; i < 4; i++) { mx = max(mx, smx[i]); mn = min(mn, smn[i]); }
        atomicMax(&mm[0], mx);
        atomicMin(&mm[1], mn);
    }
}

// Row-streaming fused SSIM + pool. One wave owns a 64-out-col strip x row band.
// No __syncthreads anywhere (waves are fully independent).
// CRITICAL: inner 11-phase loop has fixed trip count and NO break, so it fully
// unrolls and acc[][] indices are compile-time -> registers, not scratch.
__global__ __launch_bounds__(256) void ssim_stream(
    const float* __restrict__ x, const float* __restrict__ y,
    int H, int W, int NC, int nstrips, int nb, int B,
    const unsigned* __restrict__ mm,
    float* __restrict__ cs_sum, float* __restrict__ ssim_sum, GW gw,
    float* __restrict__ poolx, float* __restrict__ pooly, int do_pool)
{
    __shared__ float2 ring[4][2][80];

    const int wv = threadIdx.x >> 6;
    const int lane = threadIdx.x & 63;
    const int wid = blockIdx.x * 4 + wv;
    const int total = NC * nstrips * nb;
    if (wid >= total) return;

    const int band = wid % nb;
    const int t1 = wid / nb;
    const int strip = t1 % nstrips;
    const int img = t1 / nstrips;
    const int n = img / 3;

    const int Ho = H - (FILT - 1);
    const int Wo = W - (FILT - 1);
    const int out_lo = band * B;
    const int out_hi = min(out_lo + B, Ho);
    if (out_lo >= Ho) return;
    const int a = out_lo, b = out_hi + (FILT - 1);  // input rows [a, b)

    const int base = strip * 64;
    const float* xp = x + (size_t)img * H * W;
    const float* yp = y + (size_t)img * H * W;
    const int c0 = min(base + lane, W - 1);
    const int c1 = min(base + 64 + lane, W - 1);
    const bool colv = (base + lane) < Wo;

    const float mv = dec_f(mm[0]) - dec_f(mm[1]);
    const float c1c = (0.01f * mv) * (0.01f * mv);
    const float c2c = (0.03f * mv) * (0.03f * mv);

    const int Wp = W >> 1;
    const size_t pbase = (size_t)img * (H >> 1) * Wp;

    float acc[FILT][5];
#pragma unroll
    for (int s = 0; s < FILT; s++)
#pragma unroll
        for (int q = 0; q < 5; q++) acc[s][q] = 0.f;

    float lcs = 0.f, lss = 0.f;

#pragma unroll 1
    for (int r0 = a; r0 < b; r0 += FILT) {
#pragma unroll
        for (int p = 0; p < FILT; p++) {      // fixed trip count, NO break
            const int r = r0 + p;
            if (r < b) {
                const int cur = r & 1;

                // ---- stage row r (x,y interleaved) into per-wave LDS ring ----
                const float* xr = xp + (size_t)r * W;
                const float* yr = yp + (size_t)r * W;
                float2 v0;
                v0.x = xr[c0]; v0.y = yr[c0];
                ring[wv][cur][lane] = v0;
                if (lane < 10) {
                    float2 v1;
                    v1.x = xr[c1]; v1.y = yr[c1];
                    ring[wv][cur][64 + lane] = v1;
                }
                // cross-lane RAW within the wave: fence compiler + wait LDS
                __asm__ volatile("s_waitcnt lgkmcnt(0)" ::: "memory");

                // ---- horizontal 11-tap blur of x, y, x^2, y^2, xy ----
                float h0 = 0.f, h1 = 0.f, h2 = 0.f, h3 = 0.f, h4 = 0.f;
#pragma unroll
                for (int k = 0; k < FILT; k++) {
                    float2 v = ring[wv][cur][lane + k];
                    float w = gw.w[k];
                    h0 += w * v.x;
                    h1 += w * v.y;
                    h2 += w * (v.x * v.x);
                    h3 += w * (v.y * v.y);
                    h4 += w * (v.x * v.y);
                }

                // ---- vertical ring accumulation (all indices static) ----
#pragma unroll
                for (int k = 0; k < FILT; k++) {
                    const int s = (p - k + FILT) % FILT;
                    float w = gw.w[k];
                    acc[s][0] += w * h0;
                    acc[s][1] += w * h1;
                    acc[s][2] += w * h2;
                    acc[s][3] += w * h3;
                    acc[s][4] += w * h4;
                }

                // ---- emit completed output row ro = r-10 (slot e) ----
                const int e = (p + 1) % FILT;
                if (r >= a + (FILT - 1) && colv) {
                    float m1 = acc[e][0], m2 = acc[e][1];
                    float mu11 = m1 * m1, mu22 = m2 * m2, mu12 = m1 * m2;
                    float s1 = acc[e][2] - mu11;
                    float s2 = acc[e][3] - mu22;
                    float s12 = acc[e][4] - mu12;
                    float cs = __fdividef(2.f * s12 + c2c, s1 + s2 + c2c);
                    float ss = __fdividef(2.f * mu12 + c1c, mu11 + mu22 + c1c) * cs;
                    lcs += cs;
                    lss += ss;
                }
                acc[e][0] = acc[e][1] = acc[e][2] = acc[e][3] = acc[e][4] = 0.f;

                // ---- fused 2x2 avg pool on raw rows (r-1, r) ----
                if (do_pool && (r & 1) && r > a && lane < 32) {
                    const int pc = (base >> 1) + lane;
                    if (pc < Wp) {
                        float2 q00 = ring[wv][cur ^ 1][2 * lane];
                        float2 q01 = ring[wv][cur ^ 1][2 * lane + 1];
                        float2 q10 = ring[wv][cur][2 * lane];
                        float2 q11 = ring[wv][cur][2 * lane + 1];
                        size_t o = pbase + (size_t)(r >> 1) * Wp + pc;
                        poolx[o] = 0.25f * (q00.x + q01.x + q10.x + q11.x);
                        pooly[o] = 0.25f * (q00.y + q01.y + q10.y + q11.y);
                    }
                }
            }
        }
    }

    // ---- per-wave reduction + atomic ----
    for (int off = 32; off; off >>= 1) {
        lcs += __shfl_down(lcs, off);
        lss += __shfl_down(lss, off);
    }
    if (lane == 0) {
        atomicAdd(&cs_sum[n], lcs);
        atomicAdd(&ssim_sum[n], lss);
    }
}

__global__ void final_kernel(const float* __restrict__ cs_sum,
                             const float* __restrict__ ssim_sum,
                             float* __restrict__ out)
{
    const float cnt[5] = {3.f * 502 * 502, 3.f * 246 * 246, 3.f * 118 * 118,
                          3.f * 54 * 54, 3.f * 22 * 22};
    const float wts[5] = {0.0448f, 0.2856f, 0.3001f, 0.2363f, 0.1333f};
    int n = threadIdx.x;
    float ms = 0.f;
    if (n < 32) {
        float ssim = ssim_sum[4 * 32 + n] / cnt[4];
        float t = powf(ssim, wts[4]);
        ms = 1.f;
        for (int l = 0; l < 4; l++) {
            float cs = cs_sum[l * 32 + n] / cnt[l];
            ms *= powf(cs, wts[l]) * t;  // faithful: ssim^w4 inside the product
        }
    }
    for (int off = 32; off; off >>= 1) ms += __shfl_down(ms, off);
    if (threadIdx.x == 0) out[0] = ms / 32.f;
}

extern "C" void kernel_launch(void* const* d_in, const int* in_sizes, int n_in,
                              void* d_out, int out_size, void* d_ws, size_t ws_size,
                              hipStream_t stream) {
    const float* x0 = (const float*)d_in[0];
    const float* y0 = (const float*)d_in[1];
    float* out = (float*)d_out;
    float* ws = (float*)d_ws;
    unsigned* mm = (unsigned*)d_ws;
    float* cs_sum = ws + 2;
    float* ssim_sum = ws + 2 + 5 * 32;

    const int N = 32, C = 3, NC = N * C;
    const int Hs[5] = {512, 256, 128, 64, 32};

    // pyramid buffers in ws (floats), after 512-float accumulator area
    float* wp = ws + 512;
    float* pxw[5] = {nullptr, nullptr, nullptr, nullptr, nullptr};
    float* pyw[5] = {nullptr, nullptr, nullptr, nullptr, nullptr};
    for (int l = 1; l < 5; l++) {
        size_t sz = (size_t)NC * Hs[l] * Hs[l];
        pxw[l] = wp; wp += sz;
        pyw[l] = wp; wp += sz;
    }
    const float* px[5] = {x0, pxw[1], pxw[2], pxw[3], pxw[4]};
    const float* py[5] = {y0, pyw[1], pyw[2], pyw[3], pyw[4]};

    // gaussian weights (softmax of -c^2/(2*sigma^2))
    GW gw;
    {
        double tmp[FILT], s = 0.0;
        for (int k = 0; k < FILT; k++) {
            double c = (double)k - (FILT - 1) / 2.0;
            tmp[k] = exp(-c * c / (2.0 * 1.5 * 1.5));
            s += tmp[k];
        }
        for (int k = 0; k < FILT; k++) gw.w[k] = (float)(tmp[k] / s);
    }

    init_acc<<<1, 256, 0, stream>>>(mm);
    long n4 = (long)NC * 512 * 512 / 4;
    minmax_kernel<<<1024, 256, 0, stream>>>((const float4*)y0, n4, mm);

    for (int l = 0; l < 5; l++) {
        int H = Hs[l];
        int Ho = H - (FILT - 1);
        int nstrips = (Ho + 63) / 64;
        int nb = (Ho + 63) / 64;
        int B = (Ho + nb - 1) / nb;
        int total_waves = NC * nstrips * nb;
        int grid = (total_waves + 3) / 4;
        int do_pool = (l < 4) ? 1 : 0;
        ssim_stream<<<grid, 256, 0, stream>>>(
            px[l], py[l], H, H, NC, nstrips, nb, B, mm,
            cs_sum + l * 32, ssim_sum + l * 32, gw,
            do_pool ? pxw[l + 1] : nullptr,
            do_pool ? pyw[l + 1] : nullptr, do_pool);
    }
    final_kernel<<<1, 64, 0, stream>>>(cs_sum, ssim_sum, out);
}

// Round 5
// 371.947 us; speedup vs baseline: 9.6595x; 1.3068x over previous
//
#include <hip/hip_runtime.h>
#include <cmath>

#define FILT 11

struct GW { float w[FILT]; };

// ---- order-preserving float<->uint encode for atomic min/max ----
__device__ __forceinline__ unsigned enc_f(float f) {
    unsigned u = __float_as_uint(f);
    return (u & 0x80000000u) ? ~u : (u | 0x80000000u);
}
__device__ __forceinline__ float dec_f(unsigned u) {
    return (u & 0x80000000u) ? __uint_as_float(u & 0x7FFFFFFFu)
                             : __uint_as_float(~u);
}

__global__ void init_acc(unsigned* ws) {
    int t = threadIdx.x;
    if (t == 0) { ws[0] = 0u; ws[1] = 0xFFFFFFFFu; }
    for (int i = 2 + t; i < 512; i += blockDim.x) ws[i] = 0u;  // float 0.0
}

__global__ void minmax_kernel(const float4* __restrict__ t, long n4, unsigned* mm) {
    unsigned mx = 0u, mn = 0xFFFFFFFFu;
    long stride = (long)gridDim.x * blockDim.x;
    for (long i = (long)blockIdx.x * blockDim.x + threadIdx.x; i < n4; i += stride) {
        float4 v = t[i];
        unsigned a = enc_f(v.x), b = enc_f(v.y), c = enc_f(v.z), d = enc_f(v.w);
        mx = max(mx, max(max(a, b), max(c, d)));
        mn = min(mn, min(min(a, b), min(c, d)));
    }
    for (int off = 32; off; off >>= 1) {
        mx = max(mx, (unsigned)__shfl_down((int)mx, off));
        mn = min(mn, (unsigned)__shfl_down((int)mn, off));
    }
    __shared__ unsigned smx[4], smn[4];
    int wid = threadIdx.x >> 6, lane = threadIdx.x & 63;
    if (lane == 0) { smx[wid] = mx; smn[wid] = mn; }
    __syncthreads();
    if (threadIdx.x == 0) {
        for (int i = 1; i < 4; i++) { mx = max(mx, smx[i]); mn = min(mn, smn[i]); }
        atomicMax(&mm[0], mx);
        atomicMin(&mm[1], mn);
    }
}

// Row-streaming fused SSIM + pool. One wave owns a 64-out-col strip x row band.
// Software-pipelined: global loads for row r+1 issued while computing row r.
// Inner 11-phase loop: fixed trip count, no break -> fully unrolls, acc in VGPRs.
__global__ __launch_bounds__(256) void ssim_stream(
    const float* __restrict__ x, const float* __restrict__ y,
    int H, int W, int NC, int nstrips, int nb, int B,
    const unsigned* __restrict__ mm,
    float* __restrict__ cs_sum, float* __restrict__ ssim_sum, GW gw,
    float* __restrict__ poolx, float* __restrict__ pooly, int do_pool)
{
    __shared__ float2 ring[4][2][80];

    const int wv = threadIdx.x >> 6;
    const int lane = threadIdx.x & 63;
    const int wid = blockIdx.x * 4 + wv;
    const int total = NC * nstrips * nb;
    if (wid >= total) return;

    const int band = wid % nb;
    const int t1 = wid / nb;
    const int strip = t1 % nstrips;
    const int img = t1 / nstrips;
    const int n = img / 3;

    const int Ho = H - (FILT - 1);
    const int Wo = W - (FILT - 1);
    const int out_lo = band * B;
    const int out_hi = min(out_lo + B, Ho);
    if (out_lo >= Ho) return;
    const int a = out_lo, b = out_hi + (FILT - 1);  // input rows [a, b)

    const int base = strip * 64;
    const float* xp = x + (size_t)img * H * W;
    const float* yp = y + (size_t)img * H * W;
    const int c0 = min(base + lane, W - 1);
    const int c1 = min(base + 64 + lane, W - 1);
    const bool colv = (base + lane) < Wo;

    const float mv = dec_f(mm[0]) - dec_f(mm[1]);
    const float c1c = (0.01f * mv) * (0.01f * mv);
    const float c2c = (0.03f * mv) * (0.03f * mv);

    const int Wp = W >> 1;
    const size_t pbase = (size_t)img * (H >> 1) * Wp;

    float acc[FILT][5];
#pragma unroll
    for (int s = 0; s < FILT; s++)
#pragma unroll
        for (int q = 0; q < 5; q++) acc[s][q] = 0.f;

    float lcs = 0.f, lss = 0.f;

    // ---- prefetch row a into registers; pointers advance to row a+1 ----
    const float* xr = xp + (size_t)a * W;
    const float* yr = yp + (size_t)a * W;
    float pfx0 = xr[c0], pfy0 = yr[c0];
    float pfx1 = xr[c1], pfy1 = yr[c1];
    xr += W; yr += W;

#pragma unroll 1
    for (int r0 = a; r0 < b; r0 += FILT) {
#pragma unroll
        for (int p = 0; p < FILT; p++) {      // fixed trip count, NO break
            const int r = r0 + p;
            if (r < b) {
                const int cur = r & 1;

                // ---- stage prefetched row r into per-wave LDS ring ----
                float2 v0; v0.x = pfx0; v0.y = pfy0;
                ring[wv][cur][lane] = v0;
                if (lane < 10) {
                    float2 v1; v1.x = pfx1; v1.y = pfy1;
                    ring[wv][cur][64 + lane] = v1;
                }

                // ---- issue global loads for row r+1 (land during compute) ----
                if (r + 1 < b) {
                    pfx0 = xr[c0]; pfy0 = yr[c0];
                    pfx1 = xr[c1]; pfy1 = yr[c1];
                    xr += W; yr += W;
                }

                // cross-lane RAW within the wave: fence compiler + wait LDS
                __asm__ volatile("s_waitcnt lgkmcnt(0)" ::: "memory");

                // ---- horizontal 11-tap blur of x, y, x^2, y^2, xy ----
                float h0 = 0.f, h1 = 0.f, h2 = 0.f, h3 = 0.f, h4 = 0.f;
#pragma unroll
                for (int k = 0; k < FILT; k++) {
                    float2 v = ring[wv][cur][lane + k];
                    float w = gw.w[k];
                    h0 += w * v.x;
                    h1 += w * v.y;
                    h2 += w * (v.x * v.x);
                    h3 += w * (v.y * v.y);
                    h4 += w * (v.x * v.y);
                }

                // ---- vertical ring accumulation (all indices static) ----
#pragma unroll
                for (int k = 0; k < FILT; k++) {
                    const int s = (p - k + FILT) % FILT;
                    float w = gw.w[k];
                    acc[s][0] += w * h0;
                    acc[s][1] += w * h1;
                    acc[s][2] += w * h2;
                    acc[s][3] += w * h3;
                    acc[s][4] += w * h4;
                }

                // ---- emit completed output row ro = r-10 (slot e) ----
                const int e = (p + 1) % FILT;
                if (r >= a + (FILT - 1) && colv) {
                    float m1 = acc[e][0], m2 = acc[e][1];
                    float mu11 = m1 * m1, mu22 = m2 * m2, mu12 = m1 * m2;
                    float s1 = acc[e][2] - mu11;
                    float s2 = acc[e][3] - mu22;
                    float s12 = acc[e][4] - mu12;
                    float cs = __fdividef(2.f * s12 + c2c, s1 + s2 + c2c);
                    float ss = __fdividef(2.f * mu12 + c1c, mu11 + mu22 + c1c) * cs;
                    lcs += cs;
                    lss += ss;
                }
                acc[e][0] = acc[e][1] = acc[e][2] = acc[e][3] = acc[e][4] = 0.f;

                // ---- fused 2x2 avg pool on raw rows (r-1, r) ----
                if (do_pool && (r & 1) && r > a && lane < 32) {
                    const int pc = (base >> 1) + lane;
                    if (pc < Wp) {
                        float2 q00 = ring[wv][cur ^ 1][2 * lane];
                        float2 q01 = ring[wv][cur ^ 1][2 * lane + 1];
                        float2 q10 = ring[wv][cur][2 * lane];
                        float2 q11 = ring[wv][cur][2 * lane + 1];
                        size_t o = pbase + (size_t)(r >> 1) * Wp + pc;
                        poolx[o] = 0.25f * (q00.x + q01.x + q10.x + q11.x);
                        pooly[o] = 0.25f * (q00.y + q01.y + q10.y + q11.y);
                    }
                }
            }
        }
    }

    // ---- per-wave reduction + atomic ----
    for (int off = 32; off; off >>= 1) {
        lcs += __shfl_down(lcs, off);
        lss += __shfl_down(lss, off);
    }
    if (lane == 0) {
        atomicAdd(&cs_sum[n], lcs);
        atomicAdd(&ssim_sum[n], lss);
    }
}

__global__ void final_kernel(const float* __restrict__ cs_sum,
                             const float* __restrict__ ssim_sum,
                             float* __restrict__ out)
{
    const float cnt[5] = {3.f * 502 * 502, 3.f * 246 * 246, 3.f * 118 * 118,
                          3.f * 54 * 54, 3.f * 22 * 22};
    const float wts[5] = {0.0448f, 0.2856f, 0.3001f, 0.2363f, 0.1333f};
    int n = threadIdx.x;
    float ms = 0.f;
    if (n < 32) {
        float ssim = ssim_sum[4 * 32 + n] / cnt[4];
        float t = powf(ssim, wts[4]);
        ms = 1.f;
        for (int l = 0; l < 4; l++) {
            float cs = cs_sum[l * 32 + n] / cnt[l];
            ms *= powf(cs, wts[l]) * t;  // faithful: ssim^w4 inside the product
        }
    }
    for (int off = 32; off; off >>= 1) ms += __shfl_down(ms, off);
    if (threadIdx.x == 0) out[0] = ms / 32.f;
}

extern "C" void kernel_launch(void* const* d_in, const int* in_sizes, int n_in,
                              void* d_out, int out_size, void* d_ws, size_t ws_size,
                              hipStream_t stream) {
    const float* x0 = (const float*)d_in[0];
    const float* y0 = (const float*)d_in[1];
    float* out = (float*)d_out;
    float* ws = (float*)d_ws;
    unsigned* mm = (unsigned*)d_ws;
    float* cs_sum = ws + 2;
    float* ssim_sum = ws + 2 + 5 * 32;

    const int N = 32, C = 3, NC = N * C;
    const int Hs[5] = {512, 256, 128, 64, 32};

    // pyramid buffers in ws (floats), after 512-float accumulator area
    float* wp = ws + 512;
    float* pxw[5] = {nullptr, nullptr, nullptr, nullptr, nullptr};
    float* pyw[5] = {nullptr, nullptr, nullptr, nullptr, nullptr};
    for (int l = 1; l < 5; l++) {
        size_t sz = (size_t)NC * Hs[l] * Hs[l];
        pxw[l] = wp; wp += sz;
        pyw[l] = wp; wp += sz;
    }
    const float* px[5] = {x0, pxw[1], pxw[2], pxw[3], pxw[4]};
    const float* py[5] = {y0, pyw[1], pyw[2], pyw[3], pyw[4]};

    // gaussian weights (softmax of -c^2/(2*sigma^2))
    GW gw;
    {
        double tmp[FILT], s = 0.0;
        for (int k = 0; k < FILT; k++) {
            double c = (double)k - (FILT - 1) / 2.0;
            tmp[k] = exp(-c * c / (2.0 * 1.5 * 1.5));
            s += tmp[k];
        }
        for (int k = 0; k < FILT; k++) gw.w[k] = (float)(tmp[k] / s);
    }

    init_acc<<<1, 256, 0, stream>>>(mm);
    long n4 = (long)NC * 512 * 512 / 4;
    minmax_kernel<<<1024, 256, 0, stream>>>((const float4*)y0, n4, mm);

    for (int l = 0; l < 5; l++) {
        int H = Hs[l];
        int Ho = H - (FILT - 1);
        int nstrips = (Ho + 63) / 64;
        int nb = (Ho + 63) / 64;
        int B = (Ho + nb - 1) / nb;
        int total_waves = NC * nstrips * nb;
        int grid = (total_waves + 3) / 4;
        int do_pool = (l < 4) ? 1 : 0;
        ssim_stream<<<grid, 256, 0, stream>>>(
            px[l], py[l], H, H, NC, nstrips, nb, B, mm,
            cs_sum + l * 32, ssim_sum + l * 32, gw,
            do_pool ? pxw[l + 1] : nullptr,
            do_pool ? pyw[l + 1] : nullptr, do_pool);
    }
    final_kernel<<<1, 64, 0, stream>>>(cs_sum, ssim_sum, out);
}

// Round 6
// 368.048 us; speedup vs baseline: 9.7619x; 1.0106x over previous
//
#include <hip/hip_runtime.h>
#include <cmath>

#define FILT 11

typedef float v2f __attribute__((ext_vector_type(2)));

struct GW { float w[FILT]; };

// ---- order-preserving float<->uint encode for atomic min/max ----
__device__ __forceinline__ unsigned enc_f(float f) {
    unsigned u = __float_as_uint(f);
    return (u & 0x80000000u) ? ~u : (u | 0x80000000u);
}
__device__ __forceinline__ float dec_f(unsigned u) {
    return (u & 0x80000000u) ? __uint_as_float(u & 0x7FFFFFFFu)
                             : __uint_as_float(~u);
}

__global__ void init_acc(unsigned* ws) {
    int t = threadIdx.x;
    if (t == 0) { ws[0] = 0u; ws[1] = 0xFFFFFFFFu; }
    for (int i = 2 + t; i < 512; i += blockDim.x) ws[i] = 0u;  // float 0.0
}

__global__ void minmax_kernel(const float4* __restrict__ t, long n4, unsigned* mm) {
    unsigned mx = 0u, mn = 0xFFFFFFFFu;
    long stride = (long)gridDim.x * blockDim.x;
    for (long i = (long)blockIdx.x * blockDim.x + threadIdx.x; i < n4; i += stride) {
        float4 v = t[i];
        unsigned a = enc_f(v.x), b = enc_f(v.y), c = enc_f(v.z), d = enc_f(v.w);
        mx = max(mx, max(max(a, b), max(c, d)));
        mn = min(mn, min(min(a, b), min(c, d)));
    }
    for (int off = 32; off; off >>= 1) {
        mx = max(mx, (unsigned)__shfl_down((int)mx, off));
        mn = min(mn, (unsigned)__shfl_down((int)mn, off));
    }
    __shared__ unsigned smx[4], smn[4];
    int wid = threadIdx.x >> 6, lane = threadIdx.x & 63;
    if (lane == 0) { smx[wid] = mx; smn[wid] = mn; }
    __syncthreads();
    if (threadIdx.x == 0) {
        for (int i = 1; i < 4; i++) { mx = max(mx, smx[i]); mn = min(mn, smn[i]); }
        atomicMax(&mm[0], mx);
        atomicMin(&mm[1], mn);
    }
}

// Row-streaming fused SSIM + pool. One wave owns a 64-out-col strip x row band.
// Software-pipelined global prefetch; channels packed in v2f so the blur FMAs
// become v_pk_fma_f32 (2x fp32 rate on CDNA4).
__global__ __launch_bounds__(256) void ssim_stream(
    const float* __restrict__ x, const float* __restrict__ y,
    int H, int W, int NC, int nstrips, int nb, int B,
    const unsigned* __restrict__ mm,
    float* __restrict__ cs_sum, float* __restrict__ ssim_sum, GW gw,
    float* __restrict__ poolx, float* __restrict__ pooly, int do_pool)
{
    __shared__ v2f ring[4][2][80];

    const int wv = threadIdx.x >> 6;
    const int lane = threadIdx.x & 63;
    const int wid = blockIdx.x * 4 + wv;
    const int total = NC * nstrips * nb;
    if (wid >= total) return;

    const int band = wid % nb;
    const int t1 = wid / nb;
    const int strip = t1 % nstrips;
    const int img = t1 / nstrips;
    const int n = img / 3;

    const int Ho = H - (FILT - 1);
    const int Wo = W - (FILT - 1);
    const int out_lo = band * B;
    const int out_hi = min(out_lo + B, Ho);
    if (out_lo >= Ho) return;
    const int a = out_lo, b = out_hi + (FILT - 1);  // input rows [a, b)

    const int base = strip * 64;
    const float* xp = x + (size_t)img * H * W;
    const float* yp = y + (size_t)img * H * W;
    const int c0 = min(base + lane, W - 1);
    const int c1 = min(base + 64 + lane, W - 1);
    const bool colv = (base + lane) < Wo;

    const float mv = dec_f(mm[0]) - dec_f(mm[1]);
    const float c1c = (0.01f * mv) * (0.01f * mv);
    const float c2c = (0.03f * mv) * (0.03f * mv);

    const int Wp = W >> 1;
    const size_t pbase = (size_t)img * (H >> 1) * Wp;

    // packed accumulators: acc01 = (mu1,mu2) path, acc23 = (E[xx],E[yy]), acc4 = E[xy]
    v2f acc01[FILT], acc23[FILT];
    float acc4[FILT];
#pragma unroll
    for (int s = 0; s < FILT; s++) {
        acc01[s] = (v2f){0.f, 0.f};
        acc23[s] = (v2f){0.f, 0.f};
        acc4[s] = 0.f;
    }

    float lcs = 0.f, lss = 0.f;

    // ---- prefetch row a into registers; pointers advance to row a+1 ----
    const float* xr = xp + (size_t)a * W;
    const float* yr = yp + (size_t)a * W;
    float pfx0 = xr[c0], pfy0 = yr[c0];
    float pfx1 = xr[c1], pfy1 = yr[c1];
    xr += W; yr += W;

#pragma unroll 1
    for (int r0 = a; r0 < b; r0 += FILT) {
#pragma unroll
        for (int p = 0; p < FILT; p++) {      // fixed trip count, NO break
            const int r = r0 + p;
            if (r < b) {
                const int cur = r & 1;

                // ---- stage prefetched row r into per-wave LDS ring ----
                ring[wv][cur][lane] = (v2f){pfx0, pfy0};
                if (lane < 10) {
                    ring[wv][cur][64 + lane] = (v2f){pfx1, pfy1};
                }

                // ---- issue global loads for row r+1 (land during compute) ----
                if (r + 1 < b) {
                    pfx0 = xr[c0]; pfy0 = yr[c0];
                    pfx1 = xr[c1]; pfy1 = yr[c1];
                    xr += W; yr += W;
                }

                // cross-lane RAW within the wave: fence compiler + wait LDS
                __asm__ volatile("s_waitcnt lgkmcnt(0)" ::: "memory");

                // ---- horizontal 11-tap blur, channels packed ----
                v2f h01 = (v2f){0.f, 0.f};
                v2f h23 = (v2f){0.f, 0.f};
                float h4 = 0.f;
#pragma unroll
                for (int k = 0; k < FILT; k++) {
                    v2f v = ring[wv][cur][lane + k];
                    float w = gw.w[k];
                    v2f w2 = {w, w};
                    h01 = __builtin_elementwise_fma(w2, v, h01);         // pk_fma
                    v2f sq = v * v;                                      // pk_mul
                    h23 = __builtin_elementwise_fma(w2, sq, h23);        // pk_fma
                    h4 = __builtin_fmaf(w, v.x * v.y, h4);
                }

                // ---- vertical ring accumulation (all indices static) ----
#pragma unroll
                for (int k = 0; k < FILT; k++) {
                    const int s = (p - k + FILT) % FILT;
                    float w = gw.w[k];
                    v2f w2 = {w, w};
                    acc01[s] = __builtin_elementwise_fma(w2, h01, acc01[s]);
                    acc23[s] = __builtin_elementwise_fma(w2, h23, acc23[s]);
                    acc4[s] = __builtin_fmaf(w, h4, acc4[s]);
                }

                // ---- emit completed output row ro = r-10 (slot e) ----
                const int e = (p + 1) % FILT;
                if (r >= a + (FILT - 1) && colv) {
                    float m1 = acc01[e].x, m2 = acc01[e].y;
                    float mu11 = m1 * m1, mu22 = m2 * m2, mu12 = m1 * m2;
                    float s1 = acc23[e].x - mu11;
                    float s2 = acc23[e].y - mu22;
                    float s12 = acc4[e] - mu12;
                    float cs = __fdividef(2.f * s12 + c2c, s1 + s2 + c2c);
                    float ss = __fdividef(2.f * mu12 + c1c, mu11 + mu22 + c1c) * cs;
                    lcs += cs;
                    lss += ss;
                }
                acc01[e] = (v2f){0.f, 0.f};
                acc23[e] = (v2f){0.f, 0.f};
                acc4[e] = 0.f;

                // ---- fused 2x2 avg pool on raw rows (r-1, r) ----
                if (do_pool && (r & 1) && r > a && lane < 32) {
                    const int pc = (base >> 1) + lane;
                    if (pc < Wp) {
                        v2f q00 = ring[wv][cur ^ 1][2 * lane];
                        v2f q01 = ring[wv][cur ^ 1][2 * lane + 1];
                        v2f q10 = ring[wv][cur][2 * lane];
                        v2f q11 = ring[wv][cur][2 * lane + 1];
                        v2f s = (q00 + q01 + q10 + q11) * (v2f){0.25f, 0.25f};
                        size_t o = pbase + (size_t)(r >> 1) * Wp + pc;
                        poolx[o] = s.x;
                        pooly[o] = s.y;
                    }
                }
            }
        }
    }

    // ---- per-wave reduction + atomic ----
    for (int off = 32; off; off >>= 1) {
        lcs += __shfl_down(lcs, off);
        lss += __shfl_down(lss, off);
    }
    if (lane == 0) {
        atomicAdd(&cs_sum[n], lcs);
        atomicAdd(&ssim_sum[n], lss);
    }
}

__global__ void final_kernel(const float* __restrict__ cs_sum,
                             const float* __restrict__ ssim_sum,
                             float* __restrict__ out)
{
    const float cnt[5] = {3.f * 502 * 502, 3.f * 246 * 246, 3.f * 118 * 118,
                          3.f * 54 * 54, 3.f * 22 * 22};
    const float wts[5] = {0.0448f, 0.2856f, 0.3001f, 0.2363f, 0.1333f};
    int n = threadIdx.x;
    float ms = 0.f;
    if (n < 32) {
        float ssim = ssim_sum[4 * 32 + n] / cnt[4];
        float t = powf(ssim, wts[4]);
        ms = 1.f;
        for (int l = 0; l < 4; l++) {
            float cs = cs_sum[l * 32 + n] / cnt[l];
            ms *= powf(cs, wts[l]) * t;  // faithful: ssim^w4 inside the product
        }
    }
    for (int off = 32; off; off >>= 1) ms += __shfl_down(ms, off);
    if (threadIdx.x == 0) out[0] = ms / 32.f;
}

extern "C" void kernel_launch(void* const* d_in, const int* in_sizes, int n_in,
                              void* d_out, int out_size, void* d_ws, size_t ws_size,
                              hipStream_t stream) {
    const float* x0 = (const float*)d_in[0];
    const float* y0 = (const float*)d_in[1];
    float* out = (float*)d_out;
    float* ws = (float*)d_ws;
    unsigned* mm = (unsigned*)d_ws;
    float* cs_sum = ws + 2;
    float* ssim_sum = ws + 2 + 5 * 32;

    const int N = 32, C = 3, NC = N * C;
    const int Hs[5] = {512, 256, 128, 64, 32};

    // pyramid buffers in ws (floats), after 512-float accumulator area
    float* wp = ws + 512;
    float* pxw[5] = {nullptr, nullptr, nullptr, nullptr, nullptr};
    float* pyw[5] = {nullptr, nullptr, nullptr, nullptr, nullptr};
    for (int l = 1; l < 5; l++) {
        size_t sz = (size_t)NC * Hs[l] * Hs[l];
        pxw[l] = wp; wp += sz;
        pyw[l] = wp; wp += sz;
    }
    const float* px[5] = {x0, pxw[1], pxw[2], pxw[3], pxw[4]};
    const float* py[5] = {y0, pyw[1], pyw[2], pyw[3], pyw[4]};

    // gaussian weights (softmax of -c^2/(2*sigma^2))
    GW gw;
    {
        double tmp[FILT], s = 0.0;
        for (int k = 0; k < FILT; k++) {
            double c = (double)k - (FILT - 1) / 2.0;
            tmp[k] = exp(-c * c / (2.0 * 1.5 * 1.5));
            s += tmp[k];
        }
        for (int k = 0; k < FILT; k++) gw.w[k] = (float)(tmp[k] / s);
    }

    init_acc<<<1, 256, 0, stream>>>(mm);
    long n4 = (long)NC * 512 * 512 / 4;
    minmax_kernel<<<1024, 256, 0, stream>>>((const float4*)y0, n4, mm);

    for (int l = 0; l < 5; l++) {
        int H = Hs[l];
        int Ho = H - (FILT - 1);
        int nstrips = (Ho + 63) / 64;
        int nb = (Ho + 63) / 64;
        int B = (Ho + nb - 1) / nb;
        int total_waves = NC * nstrips * nb;
        int grid = (total_waves + 3) / 4;
        int do_pool = (l < 4) ? 1 : 0;
        ssim_stream<<<grid, 256, 0, stream>>>(
            px[l], py[l], H, H, NC, nstrips, nb, B, mm,
            cs_sum + l * 32, ssim_sum + l * 32, gw,
            do_pool ? pxw[l + 1] : nullptr,
            do_pool ? pyw[l + 1] : nullptr, do_pool);
    }
    final_kernel<<<1, 64, 0, stream>>>(cs_sum, ssim_sum, out);
}